// Round 1
// baseline (317.650 us; speedup 1.0000x reference)
//
#include <hip/hip_runtime.h>

// ContextualAttention: out[b,c,p] = sum_k K[b,k,c] * softmax_k( K[b,:,:] @ F[b,:,p] )
// K = rowwise-normalized (F^T + eps). Flash-style fusion, bf16 MFMA, f32 accum.

#define BATCH 8
#define CH 256
#define NPIX 4096
#define KT 64
#define WAVES 4
#define QTW 16
#define QTB (WAVES * QTW)
#define EPSV 1e-7f
#define L2E 1.4426950408889634f
#define RESCALE_TH 8.0f

using bf16x8 = __attribute__((ext_vector_type(8))) __bf16;
using bf16x4 = __attribute__((ext_vector_type(4))) __bf16;
using f32x4  = __attribute__((ext_vector_type(4))) float;

// ---------------- kernel 1: per-pixel inverse L2 norm of (F column + eps) ----
__global__ __launch_bounds__(256)
void ca_norms(const float* __restrict__ F, float* __restrict__ inv) {
  const int b = blockIdx.y;
  const int n = blockIdx.x * 256 + threadIdx.x;
  const float* Fb = F + (size_t)b * CH * NPIX + n;
  float s = 0.f;
#pragma unroll 8
  for (int c = 0; c < CH; ++c) {
    float v = Fb[(size_t)c * NPIX] + EPSV;
    s = fmaf(v, v, s);
  }
  inv[b * NPIX + n] = rsqrtf(s);
}

// ---------------- kernel 2: fused attention ---------------------------------
__global__ __launch_bounds__(256, 2)
void ca_attn(const float* __restrict__ F, const float* __restrict__ invn,
             float* __restrict__ Out) {
  // Kl[k][c]: GEMM1 A operand (rows = keys).  swizzle: c-index ^= (k&7)<<3
  // Kt[c][k]: GEMM2 A operand (rows = chans). swizzle: k-index ^= (c&7)<<3
  // Pl[w][q][k]: per-wave P buffer.           swizzle: k-index ^= (q&7)<<3
  __shared__ __align__(16) __bf16 Kl[KT][CH];           // 32 KB
  __shared__ __align__(16) __bf16 Kt[CH][KT];           // 32 KB
  __shared__ __align__(16) __bf16 Pl[WAVES][QTW][KT];   //  8 KB

  const int tid  = threadIdx.x;
  const int lane = tid & 63;
  const int w    = tid >> 6;
  const int b    = blockIdx.x;            // batch fastest -> one batch per XCD
  const int q0   = blockIdx.y * QTB;
  const int lq   = lane & 15;             // MFMA col (query)
  const int lg   = lane >> 4;             // lane group 0..3
  const int qg   = q0 + w * QTW + lq;     // this lane's query pixel

  const float* __restrict__ Fb   = F    + (size_t)b * CH * NPIX;
  const float* __restrict__ invb = invn + b * NPIX;

  // Q fragments (MFMA B operand), bf16, held in registers for the whole kernel.
  // B layout: lane holds B[k = lg*8+j within 32-chunk][col = lq]
  bf16x8 qf[8];
#pragma unroll
  for (int cf = 0; cf < 8; ++cf) {
#pragma unroll
    for (int j = 0; j < 8; ++j) {
      int c = cf * 32 + lg * 8 + j;
      qf[cf][j] = (__bf16)Fb[(size_t)c * NPIX + qg];
    }
  }

  const f32x4 zero = {0.f, 0.f, 0.f, 0.f};
  f32x4 oacc[16];
#pragma unroll
  for (int i = 0; i < 16; ++i) oacc[i] = zero;
  float m = -1e30f, l = 0.f;

  // staging roles
  const int iA  = tid & 15;   // float4 column index within key tile
  const int crA = tid >> 4;   // channel row (step 16)
  const int kB  = tid & 63;   // key index for Kl staging
  const int cqB = tid >> 6;   // channel quadrant for Kl staging

  for (int kt0 = 0; kt0 < NPIX; kt0 += KT) {
    // ---- stage Kt[c][k] = (F[c][k]+eps)*inv[k]  (coalesced float4 reads) ----
    {
      const float4 iv = *(const float4*)&invb[kt0 + 4 * iA];
#pragma unroll 8
      for (int rep = 0; rep < 16; ++rep) {
        int c = rep * 16 + crA;
        float4 v = *(const float4*)&Fb[(size_t)c * NPIX + kt0 + 4 * iA];
        bf16x4 o;
        o[0] = (__bf16)((v.x + EPSV) * iv.x);
        o[1] = (__bf16)((v.y + EPSV) * iv.y);
        o[2] = (__bf16)((v.z + EPSV) * iv.z);
        o[3] = (__bf16)((v.w + EPSV) * iv.w);
        *(bf16x4*)&Kt[c][(4 * iA) ^ ((c & 7) << 3)] = o;
      }
    }
    // ---- stage Kl[k][c]: gather 8 channels per key (coalesced across lanes) --
    {
      const float iv = invb[kt0 + kB];
#pragma unroll 2
      for (int rep = 0; rep < 8; ++rep) {
        int c0 = cqB * 8 + rep * 32;
        bf16x8 o;
#pragma unroll
        for (int j = 0; j < 8; ++j) {
          float v = Fb[(size_t)(c0 + j) * NPIX + kt0 + kB];
          o[j] = (__bf16)((v + EPSV) * iv);
        }
        *(bf16x8*)&Kl[kB][c0 ^ ((kB & 7) << 3)] = o;
      }
    }
    __syncthreads();

    // ---- GEMM1: S[k][q] = sum_c Kl[k][c] * Q[c][q] --------------------------
    f32x4 s[4];
#pragma unroll
    for (int ts = 0; ts < 4; ++ts) {
      s[ts] = zero;
      const int krow = ts * 16 + lq;     // A row = lane&15
#pragma unroll
      for (int cf = 0; cf < 8; ++cf) {
        bf16x8 a = *(const bf16x8*)&Kl[krow][(cf * 32 + lg * 8) ^ ((krow & 7) << 3)];
        s[ts] = __builtin_amdgcn_mfma_f32_16x16x32_bf16(a, qf[cf], s[ts], 0, 0, 0);
      }
    }

    // ---- online softmax over k (D layout: col=lq, row=lg*4+r) ---------------
    float pm = -3.0e38f;
#pragma unroll
    for (int ts = 0; ts < 4; ++ts)
#pragma unroll
      for (int r = 0; r < 4; ++r) pm = fmaxf(pm, s[ts][r]);
    pm = fmaxf(pm, __shfl_xor(pm, 16, 64));
    pm = fmaxf(pm, __shfl_xor(pm, 32, 64));

    if (!__all((pm - m) <= RESCALE_TH)) {     // defer-max (T13)
      float mn = fmaxf(m, pm);
      float sc = exp2f((m - mn) * L2E);
      l *= sc;
#pragma unroll
      for (int i = 0; i < 16; ++i) {
        oacc[i][0] *= sc; oacc[i][1] *= sc;
        oacc[i][2] *= sc; oacc[i][3] *= sc;
      }
      m = mn;
    }

    float lsum = 0.f;
#pragma unroll
    for (int ts = 0; ts < 4; ++ts) {
      bf16x4 pv;
#pragma unroll
      for (int r = 0; r < 4; ++r) {
        float p = exp2f((s[ts][r] - m) * L2E);
        lsum += p;
        pv[r] = (__bf16)p;
      }
      // rows ts*16 + lg*4 + [0..4) for column lq, swizzled by lq
      *(bf16x4*)&Pl[w][lq][(ts * 16 + lg * 4) ^ ((lq & 7) << 3)] = pv;
    }
    lsum += __shfl_xor(lsum, 16, 64);
    lsum += __shfl_xor(lsum, 32, 64);
    l += lsum;

    // ---- GEMM2: O[c][q] += sum_k Kt[c][k] * P[k][q] --------------------------
#pragma unroll
    for (int kf = 0; kf < 2; ++kf) {
      bf16x8 pf = *(const bf16x8*)&Pl[w][lq][(kf * 32 + lg * 8) ^ ((lq & 7) << 3)];
#pragma unroll
      for (int cs2 = 0; cs2 < 16; ++cs2) {
        const int c = cs2 * 16 + lq;     // A row = lane&15
        bf16x8 a = *(const bf16x8*)&Kt[c][(kf * 32 + lg * 8) ^ ((c & 7) << 3)];
        oacc[cs2] = __builtin_amdgcn_mfma_f32_16x16x32_bf16(a, pf, oacc[cs2], 0, 0, 0);
      }
    }
    __syncthreads();
  }

  // ---- epilogue: out = oacc / l --------------------------------------------
  const float rl = 1.0f / l;
  float* __restrict__ Ob = Out + (size_t)b * CH * NPIX;
#pragma unroll
  for (int cs2 = 0; cs2 < 16; ++cs2) {
#pragma unroll
    for (int r = 0; r < 4; ++r) {
      int c = cs2 * 16 + lg * 4 + r;
      Ob[(size_t)c * NPIX + qg] = oacc[cs2][r] * rl;
    }
  }
}

extern "C" void kernel_launch(void* const* d_in, const int* in_sizes, int n_in,
                              void* d_out, int out_size, void* d_ws, size_t ws_size,
                              hipStream_t stream) {
  const float* F = (const float*)d_in[0];
  float* out  = (float*)d_out;
  float* invn = (float*)d_ws;   // BATCH*NPIX floats = 128 KB

  ca_norms<<<dim3(NPIX / 256, BATCH), 256, 0, stream>>>(F, invn);
  ca_attn<<<dim3(BATCH, NPIX / QTB), 256, 0, stream>>>(F, invn, out);
}